// Round 3
// baseline (81.680 us; speedup 1.0000x reference)
//
#include <hip/hip_runtime.h>
#include <math.h>

// NoisyTopKGating via fp16x2-split MFMA, pipelined.
// out layout (f32 flat): weights [N,2] @0, indices-as-float [N,2] @32768, clean [N,64] @65536.
// d_ws: wh [128][2048] f16 (512KB) @0, wl' (=(w-wh)*2048 as f16) @524288.

constexpr int NROWS = 16384;
constexpr int DDIM  = 2048;
constexpr int EDIM  = 64;
constexpr int ECOL  = 128;            // gate cols 0..63, noise cols 64..127
constexpr int BM    = 32;             // rows per block
constexpr int NITER = 32;             // K chunks of 64
constexpr int LSTR  = 132;            // epilogue LDS stride (floats)
constexpr int IDX_OFF   = NROWS * 2;
constexpr int CLEAN_OFF = NROWS * 4;

typedef _Float16 f16x8 __attribute__((ext_vector_type(8)));
typedef float    f32x4 __attribute__((ext_vector_type(4)));

__device__ __forceinline__ float softplus_f(float z) {
    return fmaxf(z, 0.0f) + log1pf(expf(-fabsf(z)));
}

// ---------- pre-kernel: split combined weights into f16 hi + scaled-lo ----------
__global__ __launch_bounds__(256) void split_w_kernel(
    const float* __restrict__ Wg, const float* __restrict__ Wn,
    _Float16* __restrict__ wh, _Float16* __restrict__ wl)
{
    const int t  = blockIdx.x * 256 + threadIdx.x;   // 0..65535
    const int E4 = t * 4;
    const int row = E4 >> 11;
    const int k   = E4 & 2047;
    const float* src = (row < 64) ? &Wg[(size_t)row * DDIM + k]
                                  : &Wn[(size_t)(row - 64) * DDIM + k];
    const float4 v = *reinterpret_cast<const float4*>(src);
    union { _Float16 h[4]; uint2 u; } hh, ll;
    hh.h[0] = (_Float16)v.x; ll.h[0] = (_Float16)((v.x - (float)hh.h[0]) * 2048.0f);
    hh.h[1] = (_Float16)v.y; ll.h[1] = (_Float16)((v.y - (float)hh.h[1]) * 2048.0f);
    hh.h[2] = (_Float16)v.z; ll.h[2] = (_Float16)((v.z - (float)hh.h[2]) * 2048.0f);
    hh.h[3] = (_Float16)v.w; ll.h[3] = (_Float16)((v.w - (float)hh.h[3]) * 2048.0f);
    *reinterpret_cast<uint2*>(&wh[E4]) = hh.u;
    *reinterpret_cast<uint2*>(&wl[E4]) = ll.u;
}

// ---------- main fused kernel ----------
__global__ __launch_bounds__(256, 2) void gating_mfma_kernel(
    const float* __restrict__ x,
    const float* __restrict__ noise,
    const _Float16* __restrict__ whp,
    const _Float16* __restrict__ wlp,
    float* __restrict__ out)
{
    // LDS: 3 buffers x 8KB. Buffer: xh [8 blk][32 row][16B] @+0, xl @+4096.
    // blk = k-subchunk of 8 halves; row rotated by +blk (mod 32) for write-bank spread.
    __shared__ __align__(16) unsigned char smem[24576];

    const int tid = threadIdx.x;
    const int row_base = blockIdx.x * BM;
    const int lane = tid & 63;
    const int wid  = tid >> 6;           // 0..3
    const int g    = lane >> 4;          // k-group 0..3
    const int idx  = lane & 15;
    const int colbase = wid * 32;

    // ---- x staging mapping: thread -> rows (tid>>4, +16), float4 #(tid&15) of 64-float chunk
    const int srow = tid >> 4;           // 0..15
    const int kq   = tid & 15;           // float4 index
    const int blkw = kq >> 1;            // 0..7
    const int ow   = (kq & 1) * 8;       // byte offset within 16B row slot
    const int wr0 = blkw * 512 + (((srow)      + blkw) & 31) * 16 + ow;
    const int wr1 = blkw * 512 + (((srow + 16) + blkw) & 31) * 16 + ow;
    const float* xg0 = x + (size_t)(row_base + srow) * DDIM + kq * 4;
    const float* xg1 = xg0 + (size_t)16 * DDIM;

    // ---- A-frag read offsets (precomputed, rotation folded in)
    int roff[2][2];
    #pragma unroll
    for (int s = 0; s < 2; ++s)
        #pragma unroll
        for (int rf = 0; rf < 2; ++rf) {
            const int blkr = s * 4 + g;
            roff[s][rf] = blkr * 512 + (((rf * 16 + idx) + blkr) & 31) * 16;
        }

    // ---- B pointers
    const int colA = colbase + idx;
    const int colB = colbase + 16 + idx;
    const _Float16* bA = whp + (size_t)colA * DDIM + g * 8;
    const _Float16* bB = whp + (size_t)colB * DDIM + g * 8;
    const _Float16* cA = wlp + (size_t)colA * DDIM + g * 8;
    const _Float16* cB = wlp + (size_t)colB * DDIM + g * 8;

    f32x4 accm[2][2], accc[2][2];
    #pragma unroll
    for (int rf = 0; rf < 2; ++rf)
        #pragma unroll
        for (int cf = 0; cf < 2; ++cf) { accm[rf][cf] = (f32x4)0.0f; accc[rf][cf] = (f32x4)0.0f; }

    auto stage = [&](const float4 a, const float4 b, int bufoff) {
        union { _Float16 h[4]; uint2 u; } hh, ll;
        hh.h[0] = (_Float16)a.x; ll.h[0] = (_Float16)((a.x - (float)hh.h[0]) * 2048.0f);
        hh.h[1] = (_Float16)a.y; ll.h[1] = (_Float16)((a.y - (float)hh.h[1]) * 2048.0f);
        hh.h[2] = (_Float16)a.z; ll.h[2] = (_Float16)((a.z - (float)hh.h[2]) * 2048.0f);
        hh.h[3] = (_Float16)a.w; ll.h[3] = (_Float16)((a.w - (float)hh.h[3]) * 2048.0f);
        *reinterpret_cast<uint2*>(&smem[bufoff + wr0])        = hh.u;
        *reinterpret_cast<uint2*>(&smem[bufoff + 4096 + wr0]) = ll.u;
        hh.h[0] = (_Float16)b.x; ll.h[0] = (_Float16)((b.x - (float)hh.h[0]) * 2048.0f);
        hh.h[1] = (_Float16)b.y; ll.h[1] = (_Float16)((b.y - (float)hh.h[1]) * 2048.0f);
        hh.h[2] = (_Float16)b.z; ll.h[2] = (_Float16)((b.z - (float)hh.h[2]) * 2048.0f);
        hh.h[3] = (_Float16)b.w; ll.h[3] = (_Float16)((b.w - (float)hh.h[3]) * 2048.0f);
        *reinterpret_cast<uint2*>(&smem[bufoff + wr1])        = hh.u;
        *reinterpret_cast<uint2*>(&smem[bufoff + 4096 + wr1]) = ll.u;
    };

    // ---- prologue: chunks 0,1 staged; chunks 2,3 in flight; B(iter0) in regs
    float4 p0a = *reinterpret_cast<const float4*>(xg0);
    float4 p0b = *reinterpret_cast<const float4*>(xg1);
    float4 p1a = *reinterpret_cast<const float4*>(xg0 + 64);
    float4 p1b = *reinterpret_cast<const float4*>(xg1 + 64);
    stage(p0a, p0b, 0);
    p0a = *reinterpret_cast<const float4*>(xg0 + 128);
    p0b = *reinterpret_cast<const float4*>(xg1 + 128);
    stage(p1a, p1b, 8192);
    p1a = *reinterpret_cast<const float4*>(xg0 + 192);
    p1b = *reinterpret_cast<const float4*>(xg1 + 192);

    f16x8 Bh[2][2], Bl[2][2];
    #pragma unroll
    for (int s = 0; s < 2; ++s) {
        Bh[s][0] = *reinterpret_cast<const f16x8*>(bA + s * 32);
        Bh[s][1] = *reinterpret_cast<const f16x8*>(bB + s * 32);
        Bl[s][0] = *reinterpret_cast<const f16x8*>(cA + s * 32);
        Bl[s][1] = *reinterpret_cast<const f16x8*>(cB + s * 32);
    }
    __syncthreads();

    // ---- K loop: 32 iterations of K=64 ----
    int rbase = 0, wbase = 16384;
    for (int t = 0; t < NITER; ++t) {
        // issue next-iter B loads
        f16x8 Bnh[2][2], Bnl[2][2];
        if (t < NITER - 1) {
            const int ko = (t + 1) * 64;
            #pragma unroll
            for (int s = 0; s < 2; ++s) {
                Bnh[s][0] = *reinterpret_cast<const f16x8*>(bA + ko + s * 32);
                Bnh[s][1] = *reinterpret_cast<const f16x8*>(bB + ko + s * 32);
                Bnl[s][0] = *reinterpret_cast<const f16x8*>(cA + ko + s * 32);
                Bnl[s][1] = *reinterpret_cast<const f16x8*>(cB + ko + s * 32);
            }
        }

        // A fragments for this chunk
        f16x8 Ah[2][2], Al[2][2];
        #pragma unroll
        for (int s = 0; s < 2; ++s)
            #pragma unroll
            for (int rf = 0; rf < 2; ++rf) {
                const int off = rbase + roff[s][rf];
                Ah[s][rf] = *reinterpret_cast<const f16x8*>(&smem[off]);
                Al[s][rf] = *reinterpret_cast<const f16x8*>(&smem[off + 4096]);
            }

        // stage chunk t+2 (loaded 2 iters ago), then reuse regs for chunk t+4
        if (t < NITER - 2) {
            if ((t & 1) == 0) {
                stage(p0a, p0b, wbase);
                if (t < NITER - 4) {
                    p0a = *reinterpret_cast<const float4*>(xg0 + (t + 4) * 64);
                    p0b = *reinterpret_cast<const float4*>(xg1 + (t + 4) * 64);
                }
            } else {
                stage(p1a, p1b, wbase);
                if (t < NITER - 4) {
                    p1a = *reinterpret_cast<const float4*>(xg0 + (t + 4) * 64);
                    p1b = *reinterpret_cast<const float4*>(xg1 + (t + 4) * 64);
                }
            }
        }

        // MFMA: 2 k-steps x 2 rf x 2 cf x 3 passes
        #pragma unroll
        for (int s = 0; s < 2; ++s)
            #pragma unroll
            for (int rf = 0; rf < 2; ++rf)
                #pragma unroll
                for (int cf = 0; cf < 2; ++cf) {
                    accm[rf][cf] = __builtin_amdgcn_mfma_f32_16x16x32_f16(Ah[s][rf], Bh[s][cf], accm[rf][cf], 0, 0, 0);
                    accc[rf][cf] = __builtin_amdgcn_mfma_f32_16x16x32_f16(Al[s][rf], Bh[s][cf], accc[rf][cf], 0, 0, 0);
                    accc[rf][cf] = __builtin_amdgcn_mfma_f32_16x16x32_f16(Ah[s][rf], Bl[s][cf], accc[rf][cf], 0, 0, 0);
                }

        if (t < NITER - 1) {
            #pragma unroll
            for (int s = 0; s < 2; ++s)
                #pragma unroll
                for (int cf = 0; cf < 2; ++cf) {
                    Bh[s][cf] = Bnh[s][cf];
                    Bl[s][cf] = Bnl[s][cf];
                }
        }
        __syncthreads();
        rbase += 8192; if (rbase == 24576) rbase = 0;
        wbase += 8192; if (wbase == 24576) wbase = 0;
    }

    // ---- epilogue: logits -> LDS [32][132] f32 ----
    float* L = reinterpret_cast<float*>(smem);
    #pragma unroll
    for (int rf = 0; rf < 2; ++rf)
        #pragma unroll
        for (int cf = 0; cf < 2; ++cf) {
            const int col = colbase + cf * 16 + idx;
            #pragma unroll
            for (int q = 0; q < 4; ++q) {
                const int lrow = rf * 16 + g * 4 + q;
                L[lrow * LSTR + col] = accm[rf][cf][q] + accc[rf][cf][q] * 4.8828125e-4f;
            }
        }
    __syncthreads();

    // ---- fused softplus/noise/top-2/softmax: 8 threads per row ----
    {
        const int row = tid >> 3;
        const int j   = tid & 7;
        const int e0  = j * 8;
        const int grow = row_base + row;

        const float4 c0 = *reinterpret_cast<const float4*>(&L[row * LSTR + e0]);
        const float4 c1 = *reinterpret_cast<const float4*>(&L[row * LSTR + e0 + 4]);
        const float4 s0 = *reinterpret_cast<const float4*>(&L[row * LSTR + 64 + e0]);
        const float4 s1 = *reinterpret_cast<const float4*>(&L[row * LSTR + 64 + e0 + 4]);
        *reinterpret_cast<float4*>(&out[CLEAN_OFF + (size_t)grow * EDIM + e0])     = c0;
        *reinterpret_cast<float4*>(&out[CLEAN_OFF + (size_t)grow * EDIM + e0 + 4]) = c1;

        const float4 z0 = *reinterpret_cast<const float4*>(&noise[(size_t)grow * EDIM + e0]);
        const float4 z1 = *reinterpret_cast<const float4*>(&noise[(size_t)grow * EDIM + e0 + 4]);

        float nv[8];
        nv[0] = fmaf(softplus_f(s0.x), z0.x, c0.x);
        nv[1] = fmaf(softplus_f(s0.y), z0.y, c0.y);
        nv[2] = fmaf(softplus_f(s0.z), z0.z, c0.z);
        nv[3] = fmaf(softplus_f(s0.w), z0.w, c0.w);
        nv[4] = fmaf(softplus_f(s1.x), z1.x, c1.x);
        nv[5] = fmaf(softplus_f(s1.y), z1.y, c1.y);
        nv[6] = fmaf(softplus_f(s1.z), z1.z, c1.z);
        nv[7] = fmaf(softplus_f(s1.w), z1.w, c1.w);

        float v0 = nv[0], v1 = -INFINITY;
        int   i0 = e0,    i1 = -1;
        #pragma unroll
        for (int m = 1; m < 8; ++m) {
            const float v = nv[m]; const int e = e0 + m;
            if (v > v0)      { v1 = v0; i1 = i0; v0 = v; i0 = e; }
            else if (v > v1) { v1 = v;  i1 = e; }
        }
        #pragma unroll
        for (int d = 1; d < 8; d <<= 1) {
            const float ov0 = __shfl_xor(v0, d); const int oi0 = __shfl_xor(i0, d);
            const float ov1 = __shfl_xor(v1, d); const int oi1 = __shfl_xor(i1, d);
            const bool aFirst = (v0 > ov0) || (v0 == ov0 && i0 < oi0);
            float n0, n1; int ni0, ni1;
            if (aFirst) {
                n0 = v0; ni0 = i0;
                const bool s = (v1 > ov0) || (v1 == ov0 && i1 < oi0);
                n1 = s ? v1 : ov0; ni1 = s ? i1 : oi0;
            } else {
                n0 = ov0; ni0 = oi0;
                const bool s = (ov1 > v0) || (ov1 == v0 && oi1 < i0);
                n1 = s ? ov1 : v0; ni1 = s ? oi1 : i0;
            }
            v0 = n0; i0 = ni0; v1 = n1; i1 = ni1;
        }
        if (j == 0) {
            const float ex = expf(v1 - v0);
            const float w0 = 1.0f / (1.0f + ex);
            const float w1 = 1.0f - w0;
            out[(size_t)grow * 2 + 0] = w0;
            out[(size_t)grow * 2 + 1] = w1;
            out[IDX_OFF + (size_t)grow * 2 + 0] = (float)i0;
            out[IDX_OFF + (size_t)grow * 2 + 1] = (float)i1;
        }
    }
}

extern "C" void kernel_launch(void* const* d_in, const int* in_sizes, int n_in,
                              void* d_out, int out_size, void* d_ws, size_t ws_size,
                              hipStream_t stream) {
    const float* x     = (const float*)d_in[0];
    const float* Wg    = (const float*)d_in[1];
    const float* Wn    = (const float*)d_in[2];
    const float* noise = (const float*)d_in[3];
    float* out = (float*)d_out;

    _Float16* wh = (_Float16*)d_ws;
    _Float16* wl = wh + (size_t)ECOL * DDIM;

    split_w_kernel<<<dim3(256), dim3(256), 0, stream>>>(Wg, Wn, wh, wl);
    gating_mfma_kernel<<<dim3(NROWS / BM), dim3(256), 0, stream>>>(x, noise, wh, wl, out);
}

// Round 5
// 73.569 us; speedup vs baseline: 1.1103x; 1.1103x over previous
//
#include <hip/hip_runtime.h>
#include <math.h>

// NoisyTopKGating via fp16x2-split MFMA, fragment-packed B + pipelined x staging.
// out layout (f32 flat): weights [N,2] @0, indices-as-float [N,2] @32768, clean [N,64] @65536.
// d_ws: Bh packed frags (512KB) @0, Bl packed frags (512KB) @+262144 f16.
// Packed layout (f16 units): [(kc*8 + wid*2 + cf)*512 + lane*8 + j]
//   col = wid*32 + cf*16 + (lane&15),  k = kc*32 + (lane>>4)*8 + j.

constexpr int NROWS = 16384;
constexpr int DDIM  = 2048;
constexpr int EDIM  = 64;
constexpr int BM    = 32;             // rows per block
constexpr int NITER = 32;             // K chunks of 64
constexpr int LSTR  = 132;            // epilogue LDS stride (floats)
constexpr int IDX_OFF   = NROWS * 2;
constexpr int CLEAN_OFF = NROWS * 4;
constexpr size_t WPACK = 262144;      // f16 elements per packed matrix (128*2048)

typedef _Float16 f16x8 __attribute__((ext_vector_type(8)));
typedef float    f32x4 __attribute__((ext_vector_type(4)));

__device__ __forceinline__ float softplus_f(float z) {
    return fmaxf(z, 0.0f) + log1pf(expf(-fabsf(z)));
}

// ---------- pre-kernel: split + pack weights into per-wave-coalesced MFMA frags ----------
__global__ __launch_bounds__(256) void split_w_kernel(
    const float* __restrict__ Wg, const float* __restrict__ Wn,
    _Float16* __restrict__ wh, _Float16* __restrict__ wl)
{
    const int t    = blockIdx.x * 256 + threadIdx.x;   // 0..32767
    const int grp  = t >> 6;                           // kc*8 + wid*2 + cf  (0..511)
    const int lane = t & 63;
    const int kc   = grp >> 3;
    const int wid  = (grp >> 1) & 3;
    const int cf   = grp & 1;
    const int col  = wid * 32 + cf * 16 + (lane & 15);
    const int k0   = kc * 32 + (lane >> 4) * 8;
    const float* src = (col < 64) ? &Wg[(size_t)col * DDIM + k0]
                                  : &Wn[(size_t)(col - 64) * DDIM + k0];
    const float4 v0 = *reinterpret_cast<const float4*>(src);
    const float4 v1 = *reinterpret_cast<const float4*>(src + 4);
    float vv[8] = {v0.x, v0.y, v0.z, v0.w, v1.x, v1.y, v1.z, v1.w};
    union { _Float16 h[8]; uint4 u; } hh, ll;
    #pragma unroll
    for (int j = 0; j < 8; ++j) {
        hh.h[j] = (_Float16)vv[j];
        ll.h[j] = (_Float16)((vv[j] - (float)hh.h[j]) * 2048.0f);
    }
    const size_t off = (size_t)grp * 512 + lane * 8;
    *reinterpret_cast<uint4*>(&wh[off]) = hh.u;
    *reinterpret_cast<uint4*>(&wl[off]) = ll.u;
}

// ---------- main fused kernel ----------
__global__ __launch_bounds__(256, 2) void gating_mfma_kernel(
    const float* __restrict__ x,
    const float* __restrict__ noise,
    const _Float16* __restrict__ whp,
    const _Float16* __restrict__ wlp,
    float* __restrict__ out)
{
    // LDS: 3 buffers x 8KB. Buffer: xh [8 blk][32 row][16B] @+0, xl @+4096.
    __shared__ __align__(16) unsigned char smem[24576];

    const int tid = threadIdx.x;
    const int row_base = blockIdx.x * BM;
    const int lane = tid & 63;
    const int wid  = tid >> 6;           // 0..3
    const int g    = lane >> 4;          // k-group 0..3
    const int idx  = lane & 15;
    const int colbase = wid * 32;

    // ---- x staging mapping: thread -> rows (tid>>4, +16), float4 #(tid&15)
    const int srow = tid >> 4;           // 0..15
    const int kq   = tid & 15;           // float4 index within 64-float chunk
    const int blkw = kq >> 1;            // 0..7
    const int ow   = (kq & 1) * 8;       // byte offset within 16B row slot
    const int wr0 = blkw * 512 + srow * 16 + ow;
    const int wr1 = blkw * 512 + (srow + 16) * 16 + ow;
    const float* xg0 = x + (size_t)(row_base + srow) * DDIM + kq * 4;
    const float* xg1 = xg0 + (size_t)16 * DDIM;

    // ---- A-frag read offsets
    int roff[2][2];
    #pragma unroll
    for (int s = 0; s < 2; ++s)
        #pragma unroll
        for (int rf = 0; rf < 2; ++rf)
            roff[s][rf] = (s * 4 + g) * 512 + (rf * 16 + idx) * 16;

    // ---- B base pointers (fragment-packed; per-wave 1KB contiguous per load)
    const _Float16* bh_base = whp + (size_t)wid * 1024 + lane * 8;
    const _Float16* bl_base = wlp + (size_t)wid * 1024 + lane * 8;

    f32x4 accm[2][2], accc[2][2];
    #pragma unroll
    for (int rf = 0; rf < 2; ++rf)
        #pragma unroll
        for (int cf = 0; cf < 2; ++cf) { accm[rf][cf] = (f32x4)0.0f; accc[rf][cf] = (f32x4)0.0f; }

    auto stage = [&](const float4 a, const float4 b, int bufoff) {
        union { _Float16 h[4]; uint2 u; } hh, ll;
        hh.h[0] = (_Float16)a.x; ll.h[0] = (_Float16)((a.x - (float)hh.h[0]) * 2048.0f);
        hh.h[1] = (_Float16)a.y; ll.h[1] = (_Float16)((a.y - (float)hh.h[1]) * 2048.0f);
        hh.h[2] = (_Float16)a.z; ll.h[2] = (_Float16)((a.z - (float)hh.h[2]) * 2048.0f);
        hh.h[3] = (_Float16)a.w; ll.h[3] = (_Float16)((a.w - (float)hh.h[3]) * 2048.0f);
        *reinterpret_cast<uint2*>(&smem[bufoff + wr0])        = hh.u;
        *reinterpret_cast<uint2*>(&smem[bufoff + 4096 + wr0]) = ll.u;
        hh.h[0] = (_Float16)b.x; ll.h[0] = (_Float16)((b.x - (float)hh.h[0]) * 2048.0f);
        hh.h[1] = (_Float16)b.y; ll.h[1] = (_Float16)((b.y - (float)hh.h[1]) * 2048.0f);
        hh.h[2] = (_Float16)b.z; ll.h[2] = (_Float16)((b.z - (float)hh.h[2]) * 2048.0f);
        hh.h[3] = (_Float16)b.w; ll.h[3] = (_Float16)((b.w - (float)hh.h[3]) * 2048.0f);
        *reinterpret_cast<uint2*>(&smem[bufoff + wr1])        = hh.u;
        *reinterpret_cast<uint2*>(&smem[bufoff + 4096 + wr1]) = ll.u;
    };

    // ---- prologue: chunks 0,1 staged; chunk 2 in flight
    float4 qa = *reinterpret_cast<const float4*>(xg0);
    float4 qb = *reinterpret_cast<const float4*>(xg1);
    stage(qa, qb, 0);
    qa = *reinterpret_cast<const float4*>(xg0 + 64);
    qb = *reinterpret_cast<const float4*>(xg1 + 64);
    stage(qa, qb, 8192);
    qa = *reinterpret_cast<const float4*>(xg0 + 128);
    qb = *reinterpret_cast<const float4*>(xg1 + 128);
    __syncthreads();

    // ---- K loop: 32 iterations of K=64; one barrier per iter ----
    int rbase = 0, wbase = 16384;
    for (int t = 0; t < NITER; ++t) {
        // 1. issue next x load first (chunk t+3, HBM/L3 latency hidden by ~1 full iter)
        float4 na, nb;
        const bool have = (t + 3 < NITER);
        if (have) {
            na = *reinterpret_cast<const float4*>(xg0 + (t + 3) * 64);
            nb = *reinterpret_cast<const float4*>(xg1 + (t + 3) * 64);
        }
        // 2. stage chunk t+2 (loaded last iter) into the free buffer
        if (t + 2 < NITER) stage(qa, qb, wbase);
        if (have) { qa = na; qb = nb; }

        // 3. compute: 2 k-steps, B loads coalesced from packed frags
        #pragma unroll
        for (int s = 0; s < 2; ++s) {
            const size_t bko = (size_t)(2 * t + s) * 4096;
            const f16x8 Bh0 = *reinterpret_cast<const f16x8*>(bh_base + bko);
            const f16x8 Bh1 = *reinterpret_cast<const f16x8*>(bh_base + bko + 512);
            const f16x8 Bl0 = *reinterpret_cast<const f16x8*>(bl_base + bko);
            const f16x8 Bl1 = *reinterpret_cast<const f16x8*>(bl_base + bko + 512);
            const f16x8 Ah0 = *reinterpret_cast<const f16x8*>(&smem[rbase + roff[s][0]]);
            const f16x8 Ah1 = *reinterpret_cast<const f16x8*>(&smem[rbase + roff[s][1]]);
            const f16x8 Al0 = *reinterpret_cast<const f16x8*>(&smem[rbase + roff[s][0] + 4096]);
            const f16x8 Al1 = *reinterpret_cast<const f16x8*>(&smem[rbase + roff[s][1] + 4096]);

            accm[0][0] = __builtin_amdgcn_mfma_f32_16x16x32_f16(Ah0, Bh0, accm[0][0], 0, 0, 0);
            accm[0][1] = __builtin_amdgcn_mfma_f32_16x16x32_f16(Ah0, Bh1, accm[0][1], 0, 0, 0);
            accm[1][0] = __builtin_amdgcn_mfma_f32_16x16x32_f16(Ah1, Bh0, accm[1][0], 0, 0, 0);
            accm[1][1] = __builtin_amdgcn_mfma_f32_16x16x32_f16(Ah1, Bh1, accm[1][1], 0, 0, 0);
            accc[0][0] = __builtin_amdgcn_mfma_f32_16x16x32_f16(Al0, Bh0, accc[0][0], 0, 0, 0);
            accc[0][1] = __builtin_amdgcn_mfma_f32_16x16x32_f16(Al0, Bh1, accc[0][1], 0, 0, 0);
            accc[1][0] = __builtin_amdgcn_mfma_f32_16x16x32_f16(Al1, Bh0, accc[1][0], 0, 0, 0);
            accc[1][1] = __builtin_amdgcn_mfma_f32_16x16x32_f16(Al1, Bh1, accc[1][1], 0, 0, 0);
            accc[0][0] = __builtin_amdgcn_mfma_f32_16x16x32_f16(Ah0, Bl0, accc[0][0], 0, 0, 0);
            accc[0][1] = __builtin_amdgcn_mfma_f32_16x16x32_f16(Ah0, Bl1, accc[0][1], 0, 0, 0);
            accc[1][0] = __builtin_amdgcn_mfma_f32_16x16x32_f16(Ah1, Bl0, accc[1][0], 0, 0, 0);
            accc[1][1] = __builtin_amdgcn_mfma_f32_16x16x32_f16(Ah1, Bl1, accc[1][1], 0, 0, 0);
        }

        __syncthreads();
        rbase += 8192; if (rbase == 24576) rbase = 0;
        wbase += 8192; if (wbase == 24576) wbase = 0;
    }

    // ---- epilogue: logits -> LDS [32][132] f32 ----
    float* L = reinterpret_cast<float*>(smem);
    #pragma unroll
    for (int rf = 0; rf < 2; ++rf)
        #pragma unroll
        for (int cf = 0; cf < 2; ++cf) {
            const int col = colbase + cf * 16 + idx;
            #pragma unroll
            for (int q = 0; q < 4; ++q) {
                const int lrow = rf * 16 + g * 4 + q;
                L[lrow * LSTR + col] = accm[rf][cf][q] + accc[rf][cf][q] * 4.8828125e-4f;
            }
        }
    __syncthreads();

    // ---- fused softplus/noise/top-2/softmax: 8 threads per row ----
    {
        const int row = tid >> 3;
        const int j   = tid & 7;
        const int e0  = j * 8;
        const int grow = row_base + row;

        const float4 c0 = *reinterpret_cast<const float4*>(&L[row * LSTR + e0]);
        const float4 c1 = *reinterpret_cast<const float4*>(&L[row * LSTR + e0 + 4]);
        const float4 s0 = *reinterpret_cast<const float4*>(&L[row * LSTR + 64 + e0]);
        const float4 s1 = *reinterpret_cast<const float4*>(&L[row * LSTR + 64 + e0 + 4]);
        *reinterpret_cast<float4*>(&out[CLEAN_OFF + (size_t)grow * EDIM + e0])     = c0;
        *reinterpret_cast<float4*>(&out[CLEAN_OFF + (size_t)grow * EDIM + e0 + 4]) = c1;

        const float4 z0 = *reinterpret_cast<const float4*>(&noise[(size_t)grow * EDIM + e0]);
        const float4 z1 = *reinterpret_cast<const float4*>(&noise[(size_t)grow * EDIM + e0 + 4]);

        float nv[8];
        nv[0] = fmaf(softplus_f(s0.x), z0.x, c0.x);
        nv[1] = fmaf(softplus_f(s0.y), z0.y, c0.y);
        nv[2] = fmaf(softplus_f(s0.z), z0.z, c0.z);
        nv[3] = fmaf(softplus_f(s0.w), z0.w, c0.w);
        nv[4] = fmaf(softplus_f(s1.x), z1.x, c1.x);
        nv[5] = fmaf(softplus_f(s1.y), z1.y, c1.y);
        nv[6] = fmaf(softplus_f(s1.z), z1.z, c1.z);
        nv[7] = fmaf(softplus_f(s1.w), z1.w, c1.w);

        float v0 = nv[0], v1 = -INFINITY;
        int   i0 = e0,    i1 = -1;
        #pragma unroll
        for (int m = 1; m < 8; ++m) {
            const float v = nv[m]; const int e = e0 + m;
            if (v > v0)      { v1 = v0; i1 = i0; v0 = v; i0 = e; }
            else if (v > v1) { v1 = v;  i1 = e; }
        }
        #pragma unroll
        for (int d = 1; d < 8; d <<= 1) {
            const float ov0 = __shfl_xor(v0, d); const int oi0 = __shfl_xor(i0, d);
            const float ov1 = __shfl_xor(v1, d); const int oi1 = __shfl_xor(i1, d);
            const bool aFirst = (v0 > ov0) || (v0 == ov0 && i0 < oi0);
            float n0, n1; int ni0, ni1;
            if (aFirst) {
                n0 = v0; ni0 = i0;
                const bool s = (v1 > ov0) || (v1 == ov0 && i1 < oi0);
                n1 = s ? v1 : ov0; ni1 = s ? i1 : oi0;
            } else {
                n0 = ov0; ni0 = oi0;
                const bool s = (ov1 > v0) || (ov1 == v0 && oi1 < i0);
                n1 = s ? ov1 : v0; ni1 = s ? oi1 : i0;
            }
            v0 = n0; i0 = ni0; v1 = n1; i1 = ni1;
        }
        if (j == 0) {
            const float ex = expf(v1 - v0);
            const float w0 = 1.0f / (1.0f + ex);
            const float w1 = 1.0f - w0;
            out[(size_t)grow * 2 + 0] = w0;
            out[(size_t)grow * 2 + 1] = w1;
            out[IDX_OFF + (size_t)grow * 2 + 0] = (float)i0;
            out[IDX_OFF + (size_t)grow * 2 + 1] = (float)i1;
        }
    }
}

extern "C" void kernel_launch(void* const* d_in, const int* in_sizes, int n_in,
                              void* d_out, int out_size, void* d_ws, size_t ws_size,
                              hipStream_t stream) {
    const float* x     = (const float*)d_in[0];
    const float* Wg    = (const float*)d_in[1];
    const float* Wn    = (const float*)d_in[2];
    const float* noise = (const float*)d_in[3];
    float* out = (float*)d_out;

    _Float16* wh = (_Float16*)d_ws;
    _Float16* wl = wh + WPACK;               // packed matrix is 262144 f16 (512KB)

    split_w_kernel<<<dim3(128), dim3(256), 0, stream>>>(Wg, Wn, wh, wl);
    gating_mfma_kernel<<<dim3(NROWS / BM), dim3(256), 0, stream>>>(x, noise, wh, wl, out);
}